// Round 5
// baseline (12.026 us; speedup 1.0000x reference)
//
#include <hip/hip_runtime.h>
#include <math.h>

#define BB 32
#define TT 200
#define NCC 10
#define FF 2048
#define KK 3
#define NBLK (2 * NCC * BB * 4)   // 2560 = (side, nc, b) x 4 F-quarters; 10 waves/CU

// Butterfly argmax across a 64-lane wave: max value, ties -> lower index.
// Matches jax.lax.top_k (descending, stable) — verified passing in R1/R2/R4.
__device__ inline void wave_argmax(float& v, int& i) {
    #pragma unroll
    for (int m = 1; m < 64; m <<= 1) {
        float ov = __shfl_xor(v, m);
        int   oi = __shfl_xor(i, m);
        if (ov > v || (ov == v && oi < i)) { v = ov; i = oi; }
    }
}

__device__ inline float wave_sum(float v) {
    #pragma unroll
    for (int m = 1; m < 64; m <<= 1) v += __shfl_xor(v, m);
    return v;
}

// ---------------------------------------------------------------------------
// Kernel 1: one WAVE per block, no LDS, no barriers.
// blk = ((side*NCC + nc)*BB + b)*4 + fc.  Each wave: masked top-3 in registers
// (vectorized loads), gather 3 quarter-rows (512 floats each) coalesced,
// sum((r0+r1+r2)^2) -> partial[blk].  nc==0 && fc==0 waves also emit BCE term.
// ---------------------------------------------------------------------------
__global__ __launch_bounds__(64) void fused_kernel(
        const float* __restrict__ abnr_magn,
        const float* __restrict__ norm_magn,
        const float* __restrict__ abnr_feats,
        const float* __restrict__ norm_feats,
        const float* __restrict__ abnr_sls,
        const float* __restrict__ norm_sls,
        const float* __restrict__ abnr_u,
        const float* __restrict__ norm_u,
        float* __restrict__ partial /* [NBLK] */,
        float* __restrict__ bce     /* [2*BB] */) {
    const int blk  = blockIdx.x;
    const int fc   = blk & 3;
    const int r    = blk >> 2;          // (side*NCC + nc)*BB + b
    const int b    = r % BB;
    const int sn   = r / BB;
    const int side = sn / NCC;
    const int nc   = sn % NCC;
    const int lane = threadIdx.x;

    const float* feats = side ? norm_feats : abnr_feats;
    const float* magn  = side ? norm_magn  : abnr_magn;
    const float* u     = side ? norm_u     : abnr_u;

    // ---- masked top-3, fully in registers (lanes 0..49 hold 4 candidates) ----
    const float scale = 1.0f / (1.0f - 0.7f);
    float vv[4];
    int   tv[4];
    if (lane < TT / 4) {
        float4 mg = *(const float4*)(magn + b * TT + lane * 4);
        float4 uu = *(const float4*)(u    + b * TT + lane * 4);
        vv[0] = mg.x * ((uu.x >= 0.7f) ? scale : 0.0f);
        vv[1] = mg.y * ((uu.y >= 0.7f) ? scale : 0.0f);
        vv[2] = mg.z * ((uu.z >= 0.7f) ? scale : 0.0f);
        vv[3] = mg.w * ((uu.w >= 0.7f) ? scale : 0.0f);
        #pragma unroll
        for (int j = 0; j < 4; ++j) tv[j] = lane * 4 + j;
    } else {
        #pragma unroll
        for (int j = 0; j < 4; ++j) { vv[j] = -INFINITY; tv[j] = 1 << 30; }
    }
    int id[KK];
    #pragma unroll
    for (int k = 0; k < KK; ++k) {
        float bv = -INFINITY;
        int   bi = 1 << 30;
        #pragma unroll
        for (int j = 0; j < 4; ++j)
            if (vv[j] > bv || (vv[j] == bv && tv[j] < bi)) { bv = vv[j]; bi = tv[j]; }
        wave_argmax(bv, bi);
        id[k] = bi;
        #pragma unroll
        for (int j = 0; j < 4; ++j)
            if (tv[j] == bi) vv[j] = -INFINITY;
    }

    // ---- gather: 3 rows x 512 floats (this F-quarter), 2 coalesced float4/row ----
    const size_t base = (size_t)(nc * BB + b) * (TT * FF) + (size_t)fc * (FF / 4) + lane * 4;
    const float* p0 = feats + base + (size_t)id[0] * FF;
    const float* p1 = feats + base + (size_t)id[1] * FF;
    const float* p2 = feats + base + (size_t)id[2] * FF;
    float4 a0 = *(const float4*)(p0);
    float4 a1 = *(const float4*)(p1);
    float4 a2 = *(const float4*)(p2);
    float4 b0 = *(const float4*)(p0 + 256);
    float4 b1 = *(const float4*)(p1 + 256);
    float4 b2 = *(const float4*)(p2 + 256);

    float m, acc = 0.0f;
    m = a0.x + a1.x + a2.x; acc += m * m;
    m = a0.y + a1.y + a2.y; acc += m * m;
    m = a0.z + a1.z + a2.z; acc += m * m;
    m = a0.w + a1.w + a2.w; acc += m * m;
    m = b0.x + b1.x + b2.x; acc += m * m;
    m = b0.y + b1.y + b2.y; acc += m * m;
    m = b0.z + b1.z + b2.z; acc += m * m;
    m = b0.w + b1.w + b2.w; acc += m * m;

    acc = wave_sum(acc);
    if (lane == 0) partial[blk] = acc;

    // ---- BCE term, once per (side, b) ----
    if (nc == 0 && fc == 0 && lane == 0) {
        const float* sls = side ? norm_sls : abnr_sls;
        float v = (sls[b * TT + id[0]] + sls[b * TT + id[1]] +
                   sls[b * TT + id[2]]) * (1.0f / 3.0f);
        bce[side * BB + b] = side ? fmaxf(logf(1.0f - v), -100.0f)
                                  : fmaxf(logf(v), -100.0f);
    }
}

// ---------------------------------------------------------------------------
// Kernel 2: one wave. Row partials are 4 consecutive floats -> float4 loads.
// ---------------------------------------------------------------------------
__global__ __launch_bounds__(64) void final_kernel(
        const float* __restrict__ partial, const float* __restrict__ bce,
        float* __restrict__ out) {
    const int lane = threadIdx.x;
    const float third = 1.0f / 3.0f;

    float s = 0.0f;
    #pragma unroll
    for (int it = 0; it < (NCC * BB) / 64; ++it) {
        int i = it * 64 + lane;                       // row index in [0, 320)
        float4 pa4 = *(const float4*)(partial + 4 * i);
        float4 pn4 = *(const float4*)(partial + 4 * (NCC * BB + i));
        float pa = (pa4.x + pa4.y) + (pa4.z + pa4.w);
        float pn = (pn4.x + pn4.y) + (pn4.z + pn4.w);
        float l2a = sqrtf(pa) * third;   // ||mean over K|| = sqrt(sum((sum rows)^2))/3
        float l2n = sqrtf(pn) * third;
        float t = fabsf(100.0f - l2a) + l2n;
        s += t * t;
    }
    s = wave_sum(s);

    float s2 = bce[lane];                // exactly 64 BCE terms, one per lane
    s2 = wave_sum(s2);

    if (lane == 0) {
        out[0] = 1e-4f * (s * (1.0f / (float)(NCC * BB)));
        out[1] = -s2 * (1.0f / (float)BB);
    }
}

extern "C" void kernel_launch(void* const* d_in, const int* in_sizes, int n_in,
                              void* d_out, int out_size, void* d_ws, size_t ws_size,
                              hipStream_t stream) {
    const float* abnr_magn  = (const float*)d_in[0];
    const float* norm_magn  = (const float*)d_in[1];
    const float* abnr_feats = (const float*)d_in[2];
    const float* norm_feats = (const float*)d_in[3];
    const float* abnr_sls   = (const float*)d_in[4];
    const float* norm_sls   = (const float*)d_in[5];
    const float* abnr_u     = (const float*)d_in[6];
    const float* norm_u     = (const float*)d_in[7];
    float* out = (float*)d_out;

    float* bce     = (float*)d_ws;                        // 64 floats
    float* partial = (float*)((char*)d_ws + 4096);        // 2560 floats, 16B-aligned

    fused_kernel<<<NBLK, 64, 0, stream>>>(abnr_magn, norm_magn,
                                          abnr_feats, norm_feats,
                                          abnr_sls, norm_sls,
                                          abnr_u, norm_u,
                                          partial, bce);
    final_kernel<<<1, 64, 0, stream>>>(partial, bce, out);
}